// Round 12
// baseline (3584.558 us; speedup 1.0000x reference)
//
#include <hip/hip_runtime.h>
#include <math.h>

#define SS 2048
#define EE 1024
#define EPSD 1e-8
#define NTH 256          // 4 waves, 1 per SIMD
#define NW  4
#define NG  32           // cosine groups
#define GS  64           // group size

#define DPP_XOR1 0xB1    // quad_perm [1,0,3,2]
#define DPP_XOR2 0x4E    // quad_perm [2,3,0,1]
#define DPP_HMIR 0x141   // row_half_mirror
#define DPP_MIR  0x140   // row_mirror

template <typename T> struct VecT;
template <> struct VecT<double> { using t2 = double __attribute__((ext_vector_type(2))); };
template <> struct VecT<float>  { using t2 = float  __attribute__((ext_vector_type(2))); };
using d2v = double __attribute__((ext_vector_type(2)));

template <int CTRL>
__device__ __forceinline__ double mov_dpp_f64(double v) {
  union { double d; unsigned long long u; } a;
  a.d = v;
  const int lo = (int)(unsigned)(a.u & 0xFFFFFFFFull);
  const int hi = (int)(unsigned)(a.u >> 32);
  const int nlo = __builtin_amdgcn_mov_dpp(lo, CTRL, 0xF, 0xF, true);
  const int nhi = __builtin_amdgcn_mov_dpp(hi, CTRL, 0xF, 0xF, true);
  union { unsigned long long u; double d; } r;
  r.u = ((unsigned long long)(unsigned)nhi << 32) | (unsigned long long)(unsigned)nlo;
  return r.d;
}

template <int CTRL>
__device__ __forceinline__ double dpp_add(double v) { return v + mov_dpp_f64<CTRL>(v); }

template <int CTRL>
__device__ __forceinline__ void amax_dpp(double& v, int& ix) {
  const double ov = mov_dpp_f64<CTRL>(v);
  const int oi = __builtin_amdgcn_mov_dpp(ix, CTRL, 0xF, 0xF, true);
  if (ov > v || (ov == v && oi < ix)) { v = ov; ix = oi; }
}

// argmax carrying the winner's packed list links as well
template <int CTRL>
__device__ __forceinline__ void amax3_dpp(double& v, int& ix, int& pk) {
  const double ov = mov_dpp_f64<CTRL>(v);
  const int oi = __builtin_amdgcn_mov_dpp(ix, CTRL, 0xF, 0xF, true);
  const int op = __builtin_amdgcn_mov_dpp(pk, CTRL, 0xF, 0xF, true);
  if (ov > v || (ov == v && oi < ix)) { v = ov; ix = oi; pk = op; }
}

__device__ __forceinline__ void foldmax(double& v, int& ix, double ov, int oi) {
  if (ov > v || (ov == v && oi < ix)) { v = ov; ix = oi; }
}
__device__ __forceinline__ void foldmax3(double& v, int& ix, int& pk,
                                         double ov, int oi, int op) {
  if (ov > v || (ov == v && oi < ix)) { v = ov; ix = oi; pk = op; }
}

__device__ __forceinline__ double packID(int ix, unsigned pk) {
  union { int i2[2]; double d; } u;
  u.i2[0] = ix; u.i2[1] = (int)pk;
  return u.d;
}
__device__ __forceinline__ void unpackID(double d, int& ix, int& pk) {
  union { double d; int i2[2]; } u;
  u.d = d;
  ix = u.i2[0]; pk = u.i2[1];
}

// 1/sqrt(x), ~1-2 ulp: v_rsq_f64 + 2 Newton iterations. (decision-safe: R6-R11)
__device__ __forceinline__ double rsqrt2(double x) {
  double y = __builtin_amdgcn_rsq(x);
  const double h = 0.5 * x;
  y = y * fma(-h * y, y, 1.5);
  y = y * fma(-h * y, y, 1.5);
  return y;
}

// 1/x, ~1 ulp: v_rcp_f64 + 2 Newton iterations. (decision-safe: R8-R11)
__device__ __forceinline__ double rcp2(double x) {
  double y = __builtin_amdgcn_rcp(x);
  y = y * fma(-x, y, 2.0);
  y = y * fma(-x, y, 2.0);
  return y;
}

__device__ __forceinline__ double wave_sum64(double v) {
#pragma unroll
  for (int off = 32; off > 0; off >>= 1) v += __shfl_down(v, off, 64);
  return v;
}

// ~1e-13-accurate branchless f64 tanh for |z| <~ 1.2. Estrin form (depth ~6).
__device__ __forceinline__ double tanh_fast(double z) {
  const double u = 0.5 * z;
  const double s = u * u;
  const double z2 = s * s;
  const double E0 = fma(2.0 / 15.0, s, -1.0 / 3.0);
  const double E1 = fma(62.0 / 2835.0, s, -17.0 / 315.0);
  const double E2 = fma(21844.0 / 6081075.0, s, -1382.0 / 155925.0);
  const double E3 = fma(6404582.0 / 10854718875.0, s, -929569.0 / 638512875.0);
  const double E4 = fma(18888466084.0 / 194896477400625.0, s,
                        -443861162.0 / 1856156927625.0);
  const double E5 = -113927491862.0 / 2900518163668125.0;
  double P = fma(z2, E5, E4);
  P = fma(z2, P, E3);
  P = fma(z2, P, E2);
  P = fma(z2, P, E1);
  P = fma(z2, P, E0);
  const double t = fma(u * s, P, u);          // tanh(z/2)
  return (2.0 * t) * rcp2(fma(t, t, 1.0));
}

template <typename T>
__global__ void banyan_init(const int* __restrict__ seqs, const float* __restrict__ emb,
                            T* __restrict__ x, double* __restrict__ norms) {
  __shared__ double sh[4];
  const int s = blockIdx.x;
  const int row = seqs[s];
  double acc = 0.0;
  for (int e = threadIdx.x; e < EE; e += 256) {
    const float v = emb[(size_t)row * EE + e];
    x[(size_t)s * EE + e] = (T)v;
    acc += (double)v * (double)v;
  }
  acc = wave_sum64(acc);
  const int lane = threadIdx.x & 63;
  const int w = threadIdx.x >> 6;
  if (lane == 0) sh[w] = acc;
  __syncthreads();
  if (threadIdx.x == 0) norms[s] = sqrt(sh[0] + sh[1] + sh[2] + sh[3]);
}

template <typename T>
__global__ void banyan_dots(const T* __restrict__ x, double* __restrict__ num) {
  __shared__ double sh[4];
  const int s = blockIdx.x;
  double acc = 0.0;
  for (int e = threadIdx.x; e < EE; e += 256) {
    acc += (double)x[(size_t)s * EE + e] * (double)x[(size_t)(s + 1) * EE + e];
  }
  acc = wave_sum64(acc);
  const int lane = threadIdx.x & 63;
  const int w = threadIdx.x >> 6;
  if (lane == 0) sh[w] = acc;
  __syncthreads();
  if (threadIdx.x == 0) num[s] = sh[0] + sh[1] + sh[2] + sh[3];
}

// R11 structure + (a) group records carry the winner's list links (no listL
// round-trip in phase 1; i/j/p loads issue together), (b) parent stores moved
// after barrier B (ack overlaps phase 3), (c) Estrin tanh. 2 barriers/step.
template <typename T>
__global__ __launch_bounds__(NTH, 1) void banyan_main(
    T* __restrict__ x, const double* __restrict__ norms_in, const double* __restrict__ num_in,
    const float* __restrict__ Wl, const float* __restrict__ Wr, const float* __restrict__ Bb,
    float* __restrict__ out) {
  __shared__ double cosL[SS];
  __shared__ double rcpN[SS];      // 1 / max(norm, eps)
  __shared__ unsigned listL[SS];   // next lo16, prev hi16 (0xFFFF = -1)
  __shared__ int next2L[SS];       // next[next[s]] (-1 = none)
  __shared__ __align__(16) double gRec[NG * 2];  // [2g]=val, [2g+1]=(idx,pk)
  __shared__ double r3v[3][16];    // [sum][row-slot: w*4 + row]

  using T2 = typename VecT<T>::t2;
  const int t = threadIdx.x;
  const int lane = t & 63;
  const int w = t >> 6;
  const int m16 = lane & 15;
  const double NEGINF = -__builtin_inf();

  for (int s = t; s < SS; s += NTH) {
    rcpN[s] = 1.0 / fmax(norms_in[s], EPSD);
    const int nx = (s + 1 < SS) ? (s + 1) : -1;
    const int pv = s - 1;
    listL[s] = ((unsigned)nx & 0xFFFFu) | (((unsigned)pv & 0xFFFFu) << 16);
    next2L[s] = (s + 2 < SS) ? (s + 2) : -1;
  }
  __syncthreads();
  for (int s = t; s < SS; s += NTH) {
    cosL[s] = (s < SS - 1) ? (num_in[s] * rcpN[s]) * rcpN[s + 1] : NEGINF;
  }
  __syncthreads();
  for (int m = 0; m < NG / NW; ++m) {
    const int g = w * (NG / NW) + m;
    double v = cosL[g * GS + lane];
    int ix = g * GS + lane;
#pragma unroll
    for (int off = 32; off > 0; off >>= 1) {
      const double ov = __shfl_down(v, off, 64);
      const int oi = __shfl_down(ix, off, 64);
      if (ov > v || (ov == v && oi < ix)) { v = ov; ix = oi; }
    }
    if (lane == 0) { gRec[2 * g] = v; gRec[2 * g + 1] = packID(ix, 0u); }
  }
  __syncthreads();
  if (t < NG) {  // fill the winner's packed links
    int ix, pk0;
    unpackID(gRec[2 * t + 1], ix, pk0);
    gRec[2 * t + 1] = packID(ix, listL[ix]);
  }
  __syncthreads();

  // Thread t owns elements {2t, 2t+1, 512+2t, 512+2t+1}.
  const int e0 = 2 * t;
  const double wl0 = (double)Wl[e0],       wl1 = (double)Wl[e0 + 1];
  const double wl2 = (double)Wl[e0 + 512], wl3 = (double)Wl[e0 + 513];
  const double wr0 = (double)Wr[e0],       wr1 = (double)Wr[e0 + 1];
  const double wr2 = (double)Wr[e0 + 512], wr3 = (double)Wr[e0 + 513];
  const double bv0 = (double)Bb[e0],       bv1 = (double)Bb[e0 + 1];
  const double bv2 = (double)Bb[e0 + 512], bv3 = (double)Bb[e0 + 513];
  int head = 0;

  for (int step = 0; step < SS - 1; ++step) {
    // ---- phase 1: argmax over 32 group records (val, idx, links) ----
    const d2v rA = *(const d2v*)&gRec[2 * m16];
    const d2v rB = *(const d2v*)&gRec[2 * (m16 + 16)];
    double v = rA.x;
    int ix, pk;
    unpackID(rA.y, ix, pk);
    {
      int ixB, pkB;
      unpackID(rB.y, ixB, pkB);
      foldmax3(v, ix, pk, rB.x, ixB, pkB);
    }
    amax3_dpp<DPP_XOR1>(v, ix, pk);
    amax3_dpp<DPP_XOR2>(v, ix, pk);
    amax3_dpp<DPP_HMIR>(v, ix, pk);
    amax3_dpp<DPP_MIR>(v, ix, pk);
    const int i = __builtin_amdgcn_readfirstlane(ix);
    const unsigned pkU = (unsigned)__builtin_amdgcn_readfirstlane(pk);
    const int j = (int)(short)(pkU & 0xFFFFu);
    const int p = (int)(short)(pkU >> 16);
    if (p < 0) head = j;
    const int p2 = (p >= 0) ? p : i;
    const int j2 = (j >= 0) ? j : i;
    // issue i/j/p rows immediately; nj read overlaps the load window
    const T2 xiA = *(const T2*)&x[(size_t)i * EE + e0];
    const T2 xiB = *(const T2*)&x[(size_t)i * EE + e0 + 512];
    const T2 xjA = *(const T2*)&x[(size_t)j2 * EE + e0];
    const T2 xjB = *(const T2*)&x[(size_t)j2 * EE + e0 + 512];
    const T2 xpA = *(const T2*)&x[(size_t)p2 * EE + e0];
    const T2 xpB = *(const T2*)&x[(size_t)p2 * EE + e0 + 512];
    const int nj_raw = next2L[i];
    const int nj = __builtin_amdgcn_readfirstlane(nj_raw);
    const int n2 = (nj >= 0) ? nj : i;
    const T2 xnA = *(const T2*)&x[(size_t)n2 * EE + e0];
    const T2 xnB = *(const T2*)&x[(size_t)n2 * EE + e0 + 512];

    // ---- phase 2: LDS pre-reads + tanh + row-partial sums ----
    const double rcpP = rcpN[p2];
    const double rcpNN = rcpN[n2];
    const unsigned lpp = listL[p2];                  // for pp (all waves)
    const int pp = (p >= 0) ? (int)(short)(lpp >> 16) : -1;
    const int gi_ = i >> 6;
    const int gp_ = (p >= 0) ? (p >> 6) : gi_;
    const int gj_ = j >> 6;
    const int grp = (w == 0) ? gi_ : (w == 1) ? gp_ : gj_;
    const int base = grp * GS + m16;
    const double c0 = cosL[base];
    const double c1 = cosL[base + 16];
    const double c2 = cosL[base + 32];
    const double c3 = cosL[base + 48];

    const double q0 = tanh_fast(fma((double)xiA.x, wl0, fma((double)xjA.x, wr0, bv0)));
    const double q1 = tanh_fast(fma((double)xiA.y, wl1, fma((double)xjA.y, wr1, bv1)));
    const double q2 = tanh_fast(fma((double)xiB.x, wl2, fma((double)xjB.x, wr2, bv2)));
    const double q3 = tanh_fast(fma((double)xiB.y, wl3, fma((double)xjB.y, wr3, bv3)));

    double s0 = fma(q0, q0, fma(q1, q1, fma(q2, q2, q3 * q3)));
    double s1 = fma((double)xpA.x, q0, fma((double)xpA.y, q1,
                fma((double)xpB.x, q2, (double)xpB.y * q3)));
    double s2 = fma(q0, (double)xnA.x, fma(q1, (double)xnA.y,
                fma(q2, (double)xnB.x, q3 * (double)xnB.y)));
    s1 = (p >= 0) ? s1 : 0.0;
    s2 = (nj >= 0) ? s2 : 0.0;
    s0 = dpp_add<DPP_XOR1>(s0); s1 = dpp_add<DPP_XOR1>(s1); s2 = dpp_add<DPP_XOR1>(s2);
    s0 = dpp_add<DPP_XOR2>(s0); s1 = dpp_add<DPP_XOR2>(s1); s2 = dpp_add<DPP_XOR2>(s2);
    s0 = dpp_add<DPP_HMIR>(s0); s1 = dpp_add<DPP_HMIR>(s1); s2 = dpp_add<DPP_HMIR>(s2);
    s0 = dpp_add<DPP_MIR>(s0);  s1 = dpp_add<DPP_MIR>(s1);  s2 = dpp_add<DPP_MIR>(s2);
    if (m16 == 0) {                  // lanes 0,16,32,48: row partials
      const int slot = w * 4 + (lane >> 4);
      r3v[0][slot] = s0; r3v[1][slot] = s1; r3v[2][slot] = s2;
    }
    __syncthreads();  // B (no global ops outstanding: drain cheap)

    // ---- phase 3: parent store (ack overlaps), fold, repair, writes ----
    {
      T2 st0; st0.x = (T)q0; st0.y = (T)q1;
      T2 st1; st1.x = (T)q2; st1.y = (T)q3;
      *(T2*)&x[(size_t)j * EE + e0] = st0;
      *(T2*)&x[(size_t)j * EE + e0 + 512] = st1;
    }
    double t0 = r3v[0][m16];
    double t1 = r3v[1][m16];
    double t2 = r3v[2][m16];
    t0 = dpp_add<DPP_XOR1>(t0); t1 = dpp_add<DPP_XOR1>(t1); t2 = dpp_add<DPP_XOR1>(t2);
    t0 = dpp_add<DPP_XOR2>(t0); t1 = dpp_add<DPP_XOR2>(t1); t2 = dpp_add<DPP_XOR2>(t2);
    t0 = dpp_add<DPP_HMIR>(t0); t1 = dpp_add<DPP_HMIR>(t1); t2 = dpp_add<DPP_HMIR>(t2);
    t0 = dpp_add<DPP_MIR>(t0);  t1 = dpp_add<DPP_MIR>(t1);  t2 = dpp_add<DPP_MIR>(t2);
    const double invnn = (t0 > EPSD * EPSD) ? rsqrt2(t0) : 1e8;
    const double cosP = (p >= 0) ? (t1 * rcpP) * invnn : NEGINF;
    const double cosJnew = (nj >= 0) ? (t2 * rcpNN) * invnn : NEGINF;
    if (w < 3) {
      // substitute the 3 changed slots, fold 4-in-register, DPP row-reduce
      double cc0 = c0, cc1 = c1, cc2 = c2, cc3 = c3;
      const int pos0 = base, pos1 = base + 16, pos2 = base + 32, pos3 = base + 48;
      if (pos0 == i) cc0 = NEGINF;
      if (p >= 0 && pos0 == p) cc0 = cosP;
      if (pos0 == j) cc0 = cosJnew;
      if (pos1 == i) cc1 = NEGINF;
      if (p >= 0 && pos1 == p) cc1 = cosP;
      if (pos1 == j) cc1 = cosJnew;
      if (pos2 == i) cc2 = NEGINF;
      if (p >= 0 && pos2 == p) cc2 = cosP;
      if (pos2 == j) cc2 = cosJnew;
      if (pos3 == i) cc3 = NEGINF;
      if (p >= 0 && pos3 == p) cc3 = cosP;
      if (pos3 == j) cc3 = cosJnew;
      double cv = cc0; int gx = pos0;
      foldmax(cv, gx, cc1, pos1);
      foldmax(cv, gx, cc2, pos2);
      foldmax(cv, gx, cc3, pos3);
      amax_dpp<DPP_XOR1>(cv, gx);
      amax_dpp<DPP_XOR2>(cv, gx);
      amax_dpp<DPP_HMIR>(cv, gx);
      amax_dpp<DPP_MIR>(cv, gx);
      // winner's packed links, substituting this merge's in-flight updates
      unsigned pkw;
      if (gx == j) {
        pkw = ((unsigned)nj & 0xFFFFu) | (((unsigned)p & 0xFFFFu) << 16);
      } else if (p >= 0 && gx == p) {
        pkw = ((unsigned)j & 0xFFFFu) | (((unsigned)pp & 0xFFFFu) << 16);
      } else {
        pkw = listL[gx];             // gx not in {p,j}: stable this step
      }
      if (lane == 0) {
        gRec[2 * grp] = cv;
        gRec[2 * grp + 1] = packID(gx, pkw);  // dup groups: same value
      }
    } else if (lane == 0) {  // wave 3: scalar LDS state updates
      cosL[i] = NEGINF;
      cosL[j] = cosJnew;
      rcpN[j] = invnn;
      listL[j] = ((unsigned)nj & 0xFFFFu) | (((unsigned)p & 0xFFFFu) << 16);
      if (p >= 0) {
        cosL[p] = cosP;
        listL[p] = (lpp & 0xFFFF0000u) | ((unsigned)j & 0xFFFFu);
        next2L[p] = nj;
        if (pp >= 0) next2L[pp] = j;
      }
    }
    __syncthreads();  // C (drains the parent store; mostly complete by now)
  }

  {
    const T2 ha = *(const T2*)&x[(size_t)head * EE + e0];
    const T2 hb = *(const T2*)&x[(size_t)head * EE + e0 + 512];
    out[e0] = (float)ha.x;
    out[e0 + 1] = (float)ha.y;
    out[e0 + 512] = (float)hb.x;
    out[e0 + 513] = (float)hb.y;
  }
}

extern "C" void kernel_launch(void* const* d_in, const int* in_sizes, int n_in,
                              void* d_out, int out_size, void* d_ws, size_t ws_size,
                              hipStream_t stream) {
  const int* seqs = (const int*)d_in[0];
  const float* emb = (const float*)d_in[1];
  const float* Wl = (const float*)d_in[2];
  const float* Wr = (const float*)d_in[3];
  const float* Bb = (const float*)d_in[4];
  float* out = (float*)d_out;

  const size_t auxBytes = 2 * (size_t)SS * sizeof(double);
  const size_t xbytesD = (size_t)SS * EE * sizeof(double);

  if (ws_size >= xbytesD + auxBytes) {
    double* x = (double*)d_ws;
    double* norms = (double*)((char*)d_ws + xbytesD);
    double* num = norms + SS;
    hipLaunchKernelGGL((banyan_init<double>), dim3(SS), dim3(256), 0, stream, seqs, emb, x, norms);
    hipLaunchKernelGGL((banyan_dots<double>), dim3(SS - 1), dim3(256), 0, stream, x, num);
    hipLaunchKernelGGL((banyan_main<double>), dim3(1), dim3(NTH), 0, stream,
                       x, norms, num, Wl, Wr, Bb, out);
  } else {
    const size_t xbytesF = (size_t)SS * EE * sizeof(float);
    float* x = (float*)d_ws;
    double* norms = (double*)((char*)d_ws + xbytesF);
    double* num = norms + SS;
    hipLaunchKernelGGL((banyan_init<float>), dim3(SS), dim3(256), 0, stream, seqs, emb, x, norms);
    hipLaunchKernelGGL((banyan_dots<float>), dim3(SS - 1), dim3(256), 0, stream, x, num);
    hipLaunchKernelGGL((banyan_main<float>), dim3(1), dim3(NTH), 0, stream,
                       x, norms, num, Wl, Wr, Bb, out);
  }
}

// Round 13
// 3532.729 us; speedup vs baseline: 1.0147x; 1.0147x over previous
//
#include <hip/hip_runtime.h>
#include <math.h>

#define SS 2048
#define EE 1024
#define EPSD 1e-8
#define NTH 256          // 4 waves, 1 per SIMD
#define NW  4
#define NG  32           // cosine groups
#define GS  64           // group size

#define DPP_XOR1 0xB1    // quad_perm [1,0,3,2]
#define DPP_XOR2 0x4E    // quad_perm [2,3,0,1]
#define DPP_HMIR 0x141   // row_half_mirror
#define DPP_MIR  0x140   // row_mirror

using f4 = float __attribute__((ext_vector_type(4)));

template <int CTRL>
__device__ __forceinline__ double mov_dpp_f64(double v) {
  union { double d; unsigned long long u; } a;
  a.d = v;
  const int lo = (int)(unsigned)(a.u & 0xFFFFFFFFull);
  const int hi = (int)(unsigned)(a.u >> 32);
  const int nlo = __builtin_amdgcn_mov_dpp(lo, CTRL, 0xF, 0xF, true);
  const int nhi = __builtin_amdgcn_mov_dpp(hi, CTRL, 0xF, 0xF, true);
  union { unsigned long long u; double d; } r;
  r.u = ((unsigned long long)(unsigned)nhi << 32) | (unsigned long long)(unsigned)nlo;
  return r.d;
}

template <int CTRL>
__device__ __forceinline__ double dpp_add(double v) { return v + mov_dpp_f64<CTRL>(v); }

template <int CTRL>
__device__ __forceinline__ void amax_dpp(double& v, int& ix) {
  const double ov = mov_dpp_f64<CTRL>(v);
  const int oi = __builtin_amdgcn_mov_dpp(ix, CTRL, 0xF, 0xF, true);
  if (ov > v || (ov == v && oi < ix)) { v = ov; ix = oi; }
}

__device__ __forceinline__ void foldmax(double& v, int& ix, double ov, int oi) {
  if (ov > v || (ov == v && oi < ix)) { v = ov; ix = oi; }
}

// 1/sqrt(x), ~1-2 ulp: v_rsq_f64 + 2 Newton iterations. (decision-safe: R6-R12)
__device__ __forceinline__ double rsqrt2(double x) {
  double y = __builtin_amdgcn_rsq(x);
  const double h = 0.5 * x;
  y = y * fma(-h * y, y, 1.5);
  y = y * fma(-h * y, y, 1.5);
  return y;
}

// 1/x, ~1 ulp: v_rcp_f64 + 2 Newton iterations. (decision-safe: R8-R12)
__device__ __forceinline__ double rcp2(double x) {
  double y = __builtin_amdgcn_rcp(x);
  y = y * fma(-x, y, 2.0);
  y = y * fma(-x, y, 2.0);
  return y;
}

__device__ __forceinline__ double wave_sum64(double v) {
#pragma unroll
  for (int off = 32; off > 0; off >>= 1) v += __shfl_down(v, off, 64);
  return v;
}

// ~1e-13-accurate branchless f64 tanh for |z| <~ 1.2. Estrin form (depth ~6).
__device__ __forceinline__ double tanh_fast(double z) {
  const double u = 0.5 * z;
  const double s = u * u;
  const double z2 = s * s;
  const double E0 = fma(2.0 / 15.0, s, -1.0 / 3.0);
  const double E1 = fma(62.0 / 2835.0, s, -17.0 / 315.0);
  const double E2 = fma(21844.0 / 6081075.0, s, -1382.0 / 155925.0);
  const double E3 = fma(6404582.0 / 10854718875.0, s, -929569.0 / 638512875.0);
  const double E4 = fma(18888466084.0 / 194896477400625.0, s,
                        -443861162.0 / 1856156927625.0);
  const double E5 = -113927491862.0 / 2900518163668125.0;
  double P = fma(z2, E5, E4);
  P = fma(z2, P, E3);
  P = fma(z2, P, E2);
  P = fma(z2, P, E1);
  P = fma(z2, P, E0);
  const double t = fma(u * s, P, u);          // tanh(z/2)
  return (2.0 * t) * rcp2(fma(t, t, 1.0));
}

__global__ void banyan_init(const int* __restrict__ seqs, const float* __restrict__ emb,
                            float* __restrict__ x, double* __restrict__ norms) {
  __shared__ double sh[4];
  const int s = blockIdx.x;
  const int row = seqs[s];
  double acc = 0.0;
  for (int e = threadIdx.x; e < EE; e += 256) {
    const float v = emb[(size_t)row * EE + e];
    x[(size_t)s * EE + e] = v;
    acc += (double)v * (double)v;
  }
  acc = wave_sum64(acc);
  const int lane = threadIdx.x & 63;
  const int w = threadIdx.x >> 6;
  if (lane == 0) sh[w] = acc;
  __syncthreads();
  if (threadIdx.x == 0) norms[s] = sqrt(sh[0] + sh[1] + sh[2] + sh[3]);
}

__global__ void banyan_dots(const float* __restrict__ x, double* __restrict__ num) {
  __shared__ double sh[4];
  const int s = blockIdx.x;
  double acc = 0.0;
  for (int e = threadIdx.x; e < EE; e += 256) {
    acc += (double)x[(size_t)s * EE + e] * (double)x[(size_t)(s + 1) * EE + e];
  }
  acc = wave_sum64(acc);
  const int lane = threadIdx.x & 63;
  const int w = threadIdx.x >> 6;
  if (lane == 0) sh[w] = acc;
  __syncthreads();
  if (threadIdx.x == 0) num[s] = sh[0] + sh[1] + sh[2] + sh[3];
}

// R11 structure (best measured) with f32 x-storage (f64 arithmetic):
// one float4 load per row per thread, half the HBM/L3 bytes per step.
__global__ __launch_bounds__(NTH, 1) void banyan_main(
    float* __restrict__ x, const double* __restrict__ norms_in, const double* __restrict__ num_in,
    const float* __restrict__ Wl, const float* __restrict__ Wr, const float* __restrict__ Bb,
    float* __restrict__ out) {
  __shared__ double cosL[SS];
  __shared__ double rcpN[SS];      // 1 / max(norm, eps)
  __shared__ unsigned listL[SS];   // next lo16, prev hi16 (0xFFFF = -1)
  __shared__ int next2L[SS];       // next[next[s]] (-1 = none)
  __shared__ double gVal[NG];
  __shared__ int gIdx[NG];
  __shared__ double r3v[3][16];    // [sum][row-slot: w*4 + row]

  const int t = threadIdx.x;
  const int lane = t & 63;
  const int w = t >> 6;
  const int m16 = lane & 15;
  const double NEGINF = -__builtin_inf();

  for (int s = t; s < SS; s += NTH) {
    rcpN[s] = 1.0 / fmax(norms_in[s], EPSD);
    const int nx = (s + 1 < SS) ? (s + 1) : -1;
    const int pv = s - 1;
    listL[s] = ((unsigned)nx & 0xFFFFu) | (((unsigned)pv & 0xFFFFu) << 16);
    next2L[s] = (s + 2 < SS) ? (s + 2) : -1;
  }
  __syncthreads();
  for (int s = t; s < SS; s += NTH) {
    cosL[s] = (s < SS - 1) ? (num_in[s] * rcpN[s]) * rcpN[s + 1] : NEGINF;
  }
  __syncthreads();
  for (int m = 0; m < NG / NW; ++m) {
    const int g = w * (NG / NW) + m;
    double v = cosL[g * GS + lane];
    int ix = g * GS + lane;
#pragma unroll
    for (int off = 32; off > 0; off >>= 1) {
      const double ov = __shfl_down(v, off, 64);
      const int oi = __shfl_down(ix, off, 64);
      if (ov > v || (ov == v && oi < ix)) { v = ov; ix = oi; }
    }
    if (lane == 0) { gVal[g] = v; gIdx[g] = ix; }
  }
  __syncthreads();

  // Thread t owns elements {4t, 4t+1, 4t+2, 4t+3} (one 16B chunk).
  const int e0 = 4 * t;
  const double wl0 = (double)Wl[e0],     wl1 = (double)Wl[e0 + 1];
  const double wl2 = (double)Wl[e0 + 2], wl3 = (double)Wl[e0 + 3];
  const double wr0 = (double)Wr[e0],     wr1 = (double)Wr[e0 + 1];
  const double wr2 = (double)Wr[e0 + 2], wr3 = (double)Wr[e0 + 3];
  const double bv0 = (double)Bb[e0],     bv1 = (double)Bb[e0 + 1];
  const double bv2 = (double)Bb[e0 + 2], bv3 = (double)Bb[e0 + 3];
  int head = 0;

  for (int step = 0; step < SS - 1; ++step) {
    // ---- phase 1: argmax over 32 group maxima, crossing-free ----
    double v = gVal[m16];
    int ix = gIdx[m16];
    {
      const double vB = gVal[m16 + 16];
      const int iB = gIdx[m16 + 16];
      foldmax(v, ix, vB, iB);
    }
    amax_dpp<DPP_XOR1>(v, ix);
    amax_dpp<DPP_XOR2>(v, ix);
    amax_dpp<DPP_HMIR>(v, ix);
    amax_dpp<DPP_MIR>(v, ix);
    const int i = __builtin_amdgcn_readfirstlane(ix);
    // issue i-row load immediately (don't wait for the list round-trip)
    const f4 xi = *(const f4*)&x[(size_t)i * EE + e0];
    const unsigned pki = listL[i];   // broadcast LDS reads
    const int nj_raw = next2L[i];
    const int j = __builtin_amdgcn_readfirstlane((int)(short)(pki & 0xFFFFu));
    const int p = __builtin_amdgcn_readfirstlane((int)(short)(pki >> 16));
    const int nj = __builtin_amdgcn_readfirstlane(nj_raw);
    if (p < 0) head = j;
    const int p2 = (p >= 0) ? p : i;
    const int n2 = (nj >= 0) ? nj : i;

    // ---- phase 2: remaining row loads (one window), tanh, row-partial sums ----
    const f4 xj = *(const f4*)&x[(size_t)j * EE + e0];
    const f4 xp = *(const f4*)&x[(size_t)p2 * EE + e0];
    const f4 xn = *(const f4*)&x[(size_t)n2 * EE + e0];
    const double rcpP = rcpN[p2];
    const double rcpNN = rcpN[n2];
    const int gi_ = i >> 6;
    const int gp_ = (p >= 0) ? (p >> 6) : gi_;
    const int gj_ = j >> 6;
    const int grp = (w == 0) ? gi_ : (w == 1) ? gp_ : gj_;
    const int base = grp * GS + m16;
    // repair-group preloads: 4 slots/lane (same-address 4-way broadcast, free)
    const double c0 = cosL[base];
    const double c1 = cosL[base + 16];
    const double c2 = cosL[base + 32];
    const double c3 = cosL[base + 48];

    const double q0 = tanh_fast(fma((double)xi.x, wl0, fma((double)xj.x, wr0, bv0)));
    const double q1 = tanh_fast(fma((double)xi.y, wl1, fma((double)xj.y, wr1, bv1)));
    const double q2 = tanh_fast(fma((double)xi.z, wl2, fma((double)xj.z, wr2, bv2)));
    const double q3 = tanh_fast(fma((double)xi.w, wl3, fma((double)xj.w, wr3, bv3)));
    f4 st;
    st.x = (float)q0; st.y = (float)q1; st.z = (float)q2; st.w = (float)q3;
    *(f4*)&x[(size_t)j * EE + e0] = st;

    double s0 = fma(q0, q0, fma(q1, q1, fma(q2, q2, q3 * q3)));
    double s1 = fma((double)xp.x, q0, fma((double)xp.y, q1,
                fma((double)xp.z, q2, (double)xp.w * q3)));
    double s2 = fma(q0, (double)xn.x, fma(q1, (double)xn.y,
                fma(q2, (double)xn.z, q3 * (double)xn.w)));
    s1 = (p >= 0) ? s1 : 0.0;
    s2 = (nj >= 0) ? s2 : 0.0;
    // DPP-only row reduce (16-lane rows); write 16 row partials
    s0 = dpp_add<DPP_XOR1>(s0); s1 = dpp_add<DPP_XOR1>(s1); s2 = dpp_add<DPP_XOR1>(s2);
    s0 = dpp_add<DPP_XOR2>(s0); s1 = dpp_add<DPP_XOR2>(s1); s2 = dpp_add<DPP_XOR2>(s2);
    s0 = dpp_add<DPP_HMIR>(s0); s1 = dpp_add<DPP_HMIR>(s1); s2 = dpp_add<DPP_HMIR>(s2);
    s0 = dpp_add<DPP_MIR>(s0);  s1 = dpp_add<DPP_MIR>(s1);  s2 = dpp_add<DPP_MIR>(s2);
    if (m16 == 0) {                  // lanes 0,16,32,48: row partials
      const int slot = w * 4 + (lane >> 4);
      r3v[0][slot] = s0; r3v[1][slot] = s1; r3v[2][slot] = s2;
    }
    __syncthreads();  // B

    // ---- phase 3: DPP fold of 16 partials + cosines + crossing-free repair ----
    double t0 = r3v[0][m16];
    double t1 = r3v[1][m16];
    double t2 = r3v[2][m16];
    t0 = dpp_add<DPP_XOR1>(t0); t1 = dpp_add<DPP_XOR1>(t1); t2 = dpp_add<DPP_XOR1>(t2);
    t0 = dpp_add<DPP_XOR2>(t0); t1 = dpp_add<DPP_XOR2>(t1); t2 = dpp_add<DPP_XOR2>(t2);
    t0 = dpp_add<DPP_HMIR>(t0); t1 = dpp_add<DPP_HMIR>(t1); t2 = dpp_add<DPP_HMIR>(t2);
    t0 = dpp_add<DPP_MIR>(t0);  t1 = dpp_add<DPP_MIR>(t1);  t2 = dpp_add<DPP_MIR>(t2);
    const double invnn = (t0 > EPSD * EPSD) ? rsqrt2(t0) : 1e8;
    const double cosP = (p >= 0) ? (t1 * rcpP) * invnn : NEGINF;
    const double cosJnew = (nj >= 0) ? (t2 * rcpNN) * invnn : NEGINF;
    if (w < 3) {
      // substitute the 3 changed slots, fold 4-in-register, DPP row-reduce
      double cc0 = c0, cc1 = c1, cc2 = c2, cc3 = c3;
      const int pos0 = base, pos1 = base + 16, pos2 = base + 32, pos3 = base + 48;
      if (pos0 == i) cc0 = NEGINF;
      if (p >= 0 && pos0 == p) cc0 = cosP;
      if (pos0 == j) cc0 = cosJnew;
      if (pos1 == i) cc1 = NEGINF;
      if (p >= 0 && pos1 == p) cc1 = cosP;
      if (pos1 == j) cc1 = cosJnew;
      if (pos2 == i) cc2 = NEGINF;
      if (p >= 0 && pos2 == p) cc2 = cosP;
      if (pos2 == j) cc2 = cosJnew;
      if (pos3 == i) cc3 = NEGINF;
      if (p >= 0 && pos3 == p) cc3 = cosP;
      if (pos3 == j) cc3 = cosJnew;
      double cv = cc0; int gx = pos0;
      foldmax(cv, gx, cc1, pos1);
      foldmax(cv, gx, cc2, pos2);
      foldmax(cv, gx, cc3, pos3);
      amax_dpp<DPP_XOR1>(cv, gx);
      amax_dpp<DPP_XOR2>(cv, gx);
      amax_dpp<DPP_HMIR>(cv, gx);
      amax_dpp<DPP_MIR>(cv, gx);
      if (lane == 0) { gVal[grp] = cv; gIdx[grp] = gx; }  // dup groups: same value
    } else if (lane == 0) {  // wave 3: scalar LDS state updates
      cosL[i] = NEGINF;
      cosL[j] = cosJnew;
      rcpN[j] = invnn;
      listL[j] = ((unsigned)nj & 0xFFFFu) | (((unsigned)p & 0xFFFFu) << 16);
      if (p >= 0) {
        cosL[p] = cosP;
        const unsigned lp = listL[p];
        listL[p] = (lp & 0xFFFF0000u) | ((unsigned)j & 0xFFFFu);
        next2L[p] = nj;
        const int pp = (int)(short)(lp >> 16);
        if (pp >= 0) next2L[pp] = j;
      }
    }
    __syncthreads();  // C
  }

  {
    const f4 h = *(const f4*)&x[(size_t)head * EE + e0];
    *(f4*)&out[e0] = h;
  }
}

extern "C" void kernel_launch(void* const* d_in, const int* in_sizes, int n_in,
                              void* d_out, int out_size, void* d_ws, size_t ws_size,
                              hipStream_t stream) {
  const int* seqs = (const int*)d_in[0];
  const float* emb = (const float*)d_in[1];
  const float* Wl = (const float*)d_in[2];
  const float* Wr = (const float*)d_in[3];
  const float* Bb = (const float*)d_in[4];
  float* out = (float*)d_out;

  // f32 storage (f64 arithmetic): 8 MB x + 32 KB aux — always fits
  // (prior rounds confirmed ws_size >= 16 MB).
  const size_t xbytesF = (size_t)SS * EE * sizeof(float);
  float* x = (float*)d_ws;
  double* norms = (double*)((char*)d_ws + xbytesF);
  double* num = norms + SS;
  hipLaunchKernelGGL(banyan_init, dim3(SS), dim3(256), 0, stream, seqs, emb, x, norms);
  hipLaunchKernelGGL(banyan_dots, dim3(SS - 1), dim3(256), 0, stream, x, num);
  hipLaunchKernelGGL(banyan_main, dim3(1), dim3(NTH), 0, stream,
                     x, norms, num, Wl, Wr, Bb, out);
}

// Round 14
// 2681.422 us; speedup vs baseline: 1.3368x; 1.3175x over previous
//
#include <hip/hip_runtime.h>
#include <math.h>

#define SS 2048
#define EE 1024
#define EPSD 1e-8
#define EPSF 1e-8f
#define NTH 256          // 4 waves, 1 per SIMD
#define NW  4
#define NG  32           // cosine groups
#define GS  64           // group size

#define DPP_XOR1 0xB1    // quad_perm [1,0,3,2]
#define DPP_XOR2 0x4E    // quad_perm [2,3,0,1]
#define DPP_HMIR 0x141   // row_half_mirror
#define DPP_MIR  0x140   // row_mirror

using f4 = float __attribute__((ext_vector_type(4)));

// ---- f32 DPP primitives (single mov_dpp per stage) ----
template <int CTRL>
__device__ __forceinline__ float mov_dpp_f32(float v) {
  union { float f; int i; } a; a.f = v;
  const int n = __builtin_amdgcn_mov_dpp(a.i, CTRL, 0xF, 0xF, true);
  union { int i; float f; } r; r.i = n;
  return r.f;
}

template <int CTRL>
__device__ __forceinline__ float dpp_addf(float v) { return v + mov_dpp_f32<CTRL>(v); }

template <int CTRL>
__device__ __forceinline__ void amax_dppf(float& v, int& ix) {
  const float ov = mov_dpp_f32<CTRL>(v);
  const int oi = __builtin_amdgcn_mov_dpp(ix, CTRL, 0xF, 0xF, true);
  if (ov > v || (ov == v && oi < ix)) { v = ov; ix = oi; }
}

__device__ __forceinline__ void foldmaxf(float& v, int& ix, float ov, int oi) {
  if (ov > v || (ov == v && oi < ix)) { v = ov; ix = oi; }
}

// f32 1/sqrt: v_rsq_f32 + 1 Newton (~1 ulp).
__device__ __forceinline__ float rsqrt1f(float x) {
  float y = __builtin_amdgcn_rsqf(x);
  y = y * fmaf(-0.5f * x * y, y, 1.5f);
  return y;
}

// f32 1/x: v_rcp_f32 + 1 Newton (~1 ulp).
__device__ __forceinline__ float rcp1f(float x) {
  float y = __builtin_amdgcn_rcpf(x);
  y = y * fmaf(-x, y, 2.0f);
  return y;
}

// f32 tanh for |z| <= ~1.2, rel err ~2e-7: odd Taylor at z/2 (7 terms) + doubling.
__device__ __forceinline__ float tanh_f32(float z) {
  const float u = 0.5f * z;
  const float s = u * u;
  float P = fmaf(s, -929569.0f / 638512875.0f, 21844.0f / 6081075.0f);  // c15,c13
  P = fmaf(s, P, -1382.0f / 155925.0f);   // c11
  P = fmaf(s, P, 62.0f / 2835.0f);        // c9
  P = fmaf(s, P, -17.0f / 315.0f);        // c7
  P = fmaf(s, P, 2.0f / 15.0f);           // c5
  P = fmaf(s, P, -1.0f / 3.0f);           // c3
  const float t = fmaf(u * s, P, u);      // tanh(z/2)
  const float den = fmaf(t, t, 1.0f);
  return (2.0f * t) * rcp1f(den);
}

__device__ __forceinline__ double wave_sum64(double v) {
#pragma unroll
  for (int off = 32; off > 0; off >>= 1) v += __shfl_down(v, off, 64);
  return v;
}

__global__ void banyan_init(const int* __restrict__ seqs, const float* __restrict__ emb,
                            float* __restrict__ x, double* __restrict__ norms) {
  __shared__ double sh[4];
  const int s = blockIdx.x;
  const int row = seqs[s];
  double acc = 0.0;
  for (int e = threadIdx.x; e < EE; e += 256) {
    const float v = emb[(size_t)row * EE + e];
    x[(size_t)s * EE + e] = v;
    acc += (double)v * (double)v;
  }
  acc = wave_sum64(acc);
  const int lane = threadIdx.x & 63;
  const int w = threadIdx.x >> 6;
  if (lane == 0) sh[w] = acc;
  __syncthreads();
  if (threadIdx.x == 0) norms[s] = sqrt(sh[0] + sh[1] + sh[2] + sh[3]);
}

__global__ void banyan_dots(const float* __restrict__ x, double* __restrict__ num) {
  __shared__ double sh[4];
  const int s = blockIdx.x;
  double acc = 0.0;
  for (int e = threadIdx.x; e < EE; e += 256) {
    acc += (double)x[(size_t)s * EE + e] * (double)x[(size_t)(s + 1) * EE + e];
  }
  acc = wave_sum64(acc);
  const int lane = threadIdx.x & 63;
  const int w = threadIdx.x >> 6;
  if (lane == 0) sh[w] = acc;
  __syncthreads();
  if (threadIdx.x == 0) num[s] = sh[0] + sh[1] + sh[2] + sh[3];
}

// R13 skeleton, all-f32 state & arithmetic (f64 only in init kernels).
// Safe by the jax-f32 envelope: the reference's own f32 pipeline reproduces
// the np-f64 merge tree within threshold, so full-f32 noise can't flip it.
__global__ __launch_bounds__(NTH, 1) void banyan_main(
    float* __restrict__ x, const double* __restrict__ norms_in, const double* __restrict__ num_in,
    const float* __restrict__ Wl, const float* __restrict__ Wr, const float* __restrict__ Bb,
    float* __restrict__ out) {
  __shared__ float cosL[SS];
  __shared__ float rcpN[SS];       // 1 / max(norm, eps)
  __shared__ unsigned listL[SS];   // next lo16, prev hi16 (0xFFFF = -1)
  __shared__ int next2L[SS];       // next[next[s]] (-1 = none)
  __shared__ float gVal[NG];
  __shared__ int gIdx[NG];
  __shared__ float r3v[3][16];     // [sum][row-slot: w*4 + row]

  const int t = threadIdx.x;
  const int lane = t & 63;
  const int w = t >> 6;
  const int m16 = lane & 15;
  const float NEGINF = -__builtin_inff();

  for (int s = t; s < SS; s += NTH) {
    rcpN[s] = (float)(1.0 / fmax(norms_in[s], EPSD));
    const int nx = (s + 1 < SS) ? (s + 1) : -1;
    const int pv = s - 1;
    listL[s] = ((unsigned)nx & 0xFFFFu) | (((unsigned)pv & 0xFFFFu) << 16);
    next2L[s] = (s + 2 < SS) ? (s + 2) : -1;
  }
  __syncthreads();
  for (int s = t; s < SS; s += NTH) {
    cosL[s] = (s < SS - 1)
                  ? (float)((num_in[s] * (double)rcpN[s]) * (double)rcpN[s + 1])
                  : NEGINF;
  }
  __syncthreads();
  for (int m = 0; m < NG / NW; ++m) {
    const int g = w * (NG / NW) + m;
    float v = cosL[g * GS + lane];
    int ix = g * GS + lane;
#pragma unroll
    for (int off = 32; off > 0; off >>= 1) {
      const float ov = __shfl_down(v, off, 64);
      const int oi = __shfl_down(ix, off, 64);
      if (ov > v || (ov == v && oi < ix)) { v = ov; ix = oi; }
    }
    if (lane == 0) { gVal[g] = v; gIdx[g] = ix; }
  }
  __syncthreads();

  // Thread t owns elements {4t, 4t+1, 4t+2, 4t+3} (one 16B chunk).
  const int e0 = 4 * t;
  const f4 wl = *(const f4*)&Wl[e0];
  const f4 wr = *(const f4*)&Wr[e0];
  const f4 bv = *(const f4*)&Bb[e0];
  int head = 0;

  for (int step = 0; step < SS - 1; ++step) {
    // ---- phase 1: argmax over 32 group maxima, crossing-free ----
    float v = gVal[m16];
    int ix = gIdx[m16];
    foldmaxf(v, ix, gVal[m16 + 16], gIdx[m16 + 16]);
    amax_dppf<DPP_XOR1>(v, ix);
    amax_dppf<DPP_XOR2>(v, ix);
    amax_dppf<DPP_HMIR>(v, ix);
    amax_dppf<DPP_MIR>(v, ix);
    const int i = __builtin_amdgcn_readfirstlane(ix);
    // issue i-row load immediately (don't wait for the list round-trip)
    const f4 xi = *(const f4*)&x[(size_t)i * EE + e0];
    const unsigned pki = listL[i];   // broadcast LDS reads
    const int nj_raw = next2L[i];
    const int j = __builtin_amdgcn_readfirstlane((int)(short)(pki & 0xFFFFu));
    const int p = __builtin_amdgcn_readfirstlane((int)(short)(pki >> 16));
    const int nj = __builtin_amdgcn_readfirstlane(nj_raw);
    if (p < 0) head = j;
    const int p2 = (p >= 0) ? p : i;
    const int n2 = (nj >= 0) ? nj : i;

    // ---- phase 2: remaining row loads (one window), tanh, row-partial sums ----
    const f4 xj = *(const f4*)&x[(size_t)j * EE + e0];
    const f4 xp = *(const f4*)&x[(size_t)p2 * EE + e0];
    const f4 xn = *(const f4*)&x[(size_t)n2 * EE + e0];
    const float rcpP = rcpN[p2];
    const float rcpNN = rcpN[n2];
    const int gi_ = i >> 6;
    const int gp_ = (p >= 0) ? (p >> 6) : gi_;
    const int gj_ = j >> 6;
    const int grp = (w == 0) ? gi_ : (w == 1) ? gp_ : gj_;
    const int base = grp * GS + m16;
    // repair-group preloads: 4 slots/lane (same-address 4-way broadcast, free)
    const float c0 = cosL[base];
    const float c1 = cosL[base + 16];
    const float c2 = cosL[base + 32];
    const float c3 = cosL[base + 48];

    const float q0 = tanh_f32(fmaf(xi.x, wl.x, fmaf(xj.x, wr.x, bv.x)));
    const float q1 = tanh_f32(fmaf(xi.y, wl.y, fmaf(xj.y, wr.y, bv.y)));
    const float q2 = tanh_f32(fmaf(xi.z, wl.z, fmaf(xj.z, wr.z, bv.z)));
    const float q3 = tanh_f32(fmaf(xi.w, wl.w, fmaf(xj.w, wr.w, bv.w)));
    f4 st; st.x = q0; st.y = q1; st.z = q2; st.w = q3;
    *(f4*)&x[(size_t)j * EE + e0] = st;

    float s0 = fmaf(q0, q0, fmaf(q1, q1, fmaf(q2, q2, q3 * q3)));
    float s1 = fmaf(xp.x, q0, fmaf(xp.y, q1, fmaf(xp.z, q2, xp.w * q3)));
    float s2 = fmaf(q0, xn.x, fmaf(q1, xn.y, fmaf(q2, xn.z, q3 * xn.w)));
    s1 = (p >= 0) ? s1 : 0.0f;
    s2 = (nj >= 0) ? s2 : 0.0f;
    // DPP-only row reduce (16-lane rows); write 16 row partials
    s0 = dpp_addf<DPP_XOR1>(s0); s1 = dpp_addf<DPP_XOR1>(s1); s2 = dpp_addf<DPP_XOR1>(s2);
    s0 = dpp_addf<DPP_XOR2>(s0); s1 = dpp_addf<DPP_XOR2>(s1); s2 = dpp_addf<DPP_XOR2>(s2);
    s0 = dpp_addf<DPP_HMIR>(s0); s1 = dpp_addf<DPP_HMIR>(s1); s2 = dpp_addf<DPP_HMIR>(s2);
    s0 = dpp_addf<DPP_MIR>(s0);  s1 = dpp_addf<DPP_MIR>(s1);  s2 = dpp_addf<DPP_MIR>(s2);
    if (m16 == 0) {                  // lanes 0,16,32,48: row partials
      const int slot = w * 4 + (lane >> 4);
      r3v[0][slot] = s0; r3v[1][slot] = s1; r3v[2][slot] = s2;
    }
    __syncthreads();  // B

    // ---- phase 3: DPP fold of 16 partials + cosines + crossing-free repair ----
    float t0 = r3v[0][m16];
    float t1 = r3v[1][m16];
    float t2 = r3v[2][m16];
    t0 = dpp_addf<DPP_XOR1>(t0); t1 = dpp_addf<DPP_XOR1>(t1); t2 = dpp_addf<DPP_XOR1>(t2);
    t0 = dpp_addf<DPP_XOR2>(t0); t1 = dpp_addf<DPP_XOR2>(t1); t2 = dpp_addf<DPP_XOR2>(t2);
    t0 = dpp_addf<DPP_HMIR>(t0); t1 = dpp_addf<DPP_HMIR>(t1); t2 = dpp_addf<DPP_HMIR>(t2);
    t0 = dpp_addf<DPP_MIR>(t0);  t1 = dpp_addf<DPP_MIR>(t1);  t2 = dpp_addf<DPP_MIR>(t2);
    const float invnn = (t0 > EPSF * EPSF) ? rsqrt1f(t0) : 1e8f;
    const float cosP = (p >= 0) ? (t1 * rcpP) * invnn : NEGINF;
    const float cosJnew = (nj >= 0) ? (t2 * rcpNN) * invnn : NEGINF;
    if (w < 3) {
      // substitute the 3 changed slots, fold 4-in-register, DPP row-reduce
      float cc0 = c0, cc1 = c1, cc2 = c2, cc3 = c3;
      const int pos0 = base, pos1 = base + 16, pos2 = base + 32, pos3 = base + 48;
      if (pos0 == i) cc0 = NEGINF;
      if (p >= 0 && pos0 == p) cc0 = cosP;
      if (pos0 == j) cc0 = cosJnew;
      if (pos1 == i) cc1 = NEGINF;
      if (p >= 0 && pos1 == p) cc1 = cosP;
      if (pos1 == j) cc1 = cosJnew;
      if (pos2 == i) cc2 = NEGINF;
      if (p >= 0 && pos2 == p) cc2 = cosP;
      if (pos2 == j) cc2 = cosJnew;
      if (pos3 == i) cc3 = NEGINF;
      if (p >= 0 && pos3 == p) cc3 = cosP;
      if (pos3 == j) cc3 = cosJnew;
      float cv = cc0; int gx = pos0;
      foldmaxf(cv, gx, cc1, pos1);
      foldmaxf(cv, gx, cc2, pos2);
      foldmaxf(cv, gx, cc3, pos3);
      amax_dppf<DPP_XOR1>(cv, gx);
      amax_dppf<DPP_XOR2>(cv, gx);
      amax_dppf<DPP_HMIR>(cv, gx);
      amax_dppf<DPP_MIR>(cv, gx);
      if (lane == 0) { gVal[grp] = cv; gIdx[grp] = gx; }  // dup groups: same value
    } else if (lane == 0) {  // wave 3: scalar LDS state updates
      cosL[i] = NEGINF;
      cosL[j] = cosJnew;
      rcpN[j] = invnn;
      listL[j] = ((unsigned)nj & 0xFFFFu) | (((unsigned)p & 0xFFFFu) << 16);
      if (p >= 0) {
        cosL[p] = cosP;
        const unsigned lp = listL[p];
        listL[p] = (lp & 0xFFFF0000u) | ((unsigned)j & 0xFFFFu);
        next2L[p] = nj;
        const int pp = (int)(short)(lp >> 16);
        if (pp >= 0) next2L[pp] = j;
      }
    }
    __syncthreads();  // C
  }

  {
    const f4 h = *(const f4*)&x[(size_t)head * EE + e0];
    *(f4*)&out[e0] = h;
  }
}

extern "C" void kernel_launch(void* const* d_in, const int* in_sizes, int n_in,
                              void* d_out, int out_size, void* d_ws, size_t ws_size,
                              hipStream_t stream) {
  const int* seqs = (const int*)d_in[0];
  const float* emb = (const float*)d_in[1];
  const float* Wl = (const float*)d_in[2];
  const float* Wr = (const float*)d_in[3];
  const float* Bb = (const float*)d_in[4];
  float* out = (float*)d_out;

  const size_t xbytesF = (size_t)SS * EE * sizeof(float);
  float* x = (float*)d_ws;
  double* norms = (double*)((char*)d_ws + xbytesF);
  double* num = norms + SS;
  hipLaunchKernelGGL(banyan_init, dim3(SS), dim3(256), 0, stream, seqs, emb, x, norms);
  hipLaunchKernelGGL(banyan_dots, dim3(SS - 1), dim3(256), 0, stream, x, num);
  hipLaunchKernelGGL(banyan_main, dim3(1), dim3(NTH), 0, stream,
                     x, norms, num, Wl, Wr, Bb, out);
}